// Round 8
// baseline (237.733 us; speedup 1.0000x reference)
//
#include <hip/hip_runtime.h>

typedef __bf16 bf16x8 __attribute__((ext_vector_type(8)));
typedef float f32x4 __attribute__((ext_vector_type(4)));

#define GLDS(g, l) __builtin_amdgcn_global_load_lds(                              \
    (const __attribute__((address_space(1))) void*)(g),                            \
    (__attribute__((address_space(3))) void*)(l), 16, 0, 0)

#define PHASE_FENCE_PRE()  __builtin_amdgcn_sched_barrier(0)
#define PHASE_FENCE_POST()                                     \
  asm volatile("s_waitcnt lgkmcnt(0)" ::: "memory");           \
  __builtin_amdgcn_sched_barrier(0)

__device__ __forceinline__ unsigned short f2bf(float f) {
  unsigned int u = __builtin_bit_cast(unsigned int, f);
  u = (u + 0x7fffu + ((u >> 16) & 1u)) >> 16;
  return (unsigned short)u;
}
__device__ __forceinline__ float bf2f(unsigned short h) {
  unsigned int u = ((unsigned int)h) << 16;
  return __builtin_bit_cast(float, u);
}

// ---------------- converts ----------------
__global__ __launch_bounds__(256) void cvt_f32_bf16(
    const float* __restrict__ in, unsigned short* __restrict__ out, int n4) {
  int i = blockIdx.x * 256 + threadIdx.x;
  if (i < n4) {
    float4 v = ((const float4*)in)[i];
    ushort4 o;
    o.x = f2bf(v.x); o.y = f2bf(v.y); o.z = f2bf(v.z); o.w = f2bf(v.w);
    ((ushort4*)out)[i] = o;
  }
}

__global__ __launch_bounds__(256) void cvt_w4(
    const float* __restrict__ w0, const float* __restrict__ w1,
    const float* __restrict__ w2, const float* __restrict__ w3,
    unsigned short* __restrict__ out) {
  const int y = blockIdx.y;
  const float* src = (y == 0) ? w0 : (y == 1) ? w1 : (y == 2) ? w2 : w3;
  const int i = blockIdx.x * 256 + threadIdx.x;
  float4 v = ((const float4*)src)[i];
  ushort4 o;
  o.x = f2bf(v.x); o.y = f2bf(v.y); o.z = f2bf(v.z); o.w = f2bf(v.w);
  ((ushort4*)(out + (size_t)y * 4194304))[i] = o;
}

// ============ QKV GEMM: m201-style 256x256 8-phase port ============
// BM=BN=256 BK=64. 8 waves 2M x 4N, wave tile 128x64 (8m x 4n frags).
// 4 quadrant-phases per K-tile: Q00(12 rd) Q10(8) Q11(4) Q01(8), 16 MFMA each,
// Af/Bf register-reused across adjacent phases. LDS 128KB: A,B each 2buf x 2half x
// [128 rows][64 cols]. Stage 1 half/phase (P1 stages 2), drain once per tile.
// Grid 16x24 = 384 (1.5 rounds — tail accepted for the wave-tile geometry).
__global__ __launch_bounds__(512, 2) void gemm256_qkv(
    const unsigned short* __restrict__ A, const unsigned short* __restrict__ Bw,
    const float* __restrict__ bq, const float* __restrict__ bk, const float* __restrict__ bv,
    unsigned short* __restrict__ oQ, unsigned short* __restrict__ oK,
    unsigned short* __restrict__ oV) {
  constexpr int K = 2048, NT = 32;
  __shared__ unsigned short lds[65536];   // A: 4 x 8192 us @0, B: 4 x 8192 us @32768
  const int tid = threadIdx.x, lane = tid & 63, wid = tid >> 6;
  const int wm = wid >> 2;         // 0..1 : M-half of tile (= A LDS half index)
  const int wn = wid & 3;          // 0..3 : 64-col strip (B half = wn>>1)

  // XCD bijective swizzle over 384 wgs
  const int g0 = blockIdx.x;
  const int wg = (g0 & 7) * 48 + (g0 >> 3);
  const int bx = wg / 16;          // 0..23 N-tiles
  const int by = wg % 16;          // 0..15 M-tiles

  // stage source: row tid>>3 within a 64-row call, chunk lane&7, XOR-preswizzled
  const int srow = tid >> 3;                               // 0..63
  const size_t gsw = (size_t)(((lane & 7) ^ (srow & 7)) << 3);
  const unsigned short* gA = A  + (size_t)(by * 256 + srow) * K + gsw;
  const unsigned short* gB = Bw + (size_t)(bx * 256 + srow) * K + gsw;

  // stage half h (128 rows) of tile tt into dbuf b:  2 glds calls (64 rows each)
#define STAGE_A(b, h, tt)                                                                    \
  do {                                                                                       \
    GLDS(gA + (size_t)((h) * 128) * K + (size_t)(tt) * 64,                                   \
         lds + ((b) * 2 + (h)) * 8192 + wid * 512);                                          \
    GLDS(gA + (size_t)((h) * 128 + 64) * K + (size_t)(tt) * 64,                              \
         lds + ((b) * 2 + (h)) * 8192 + 4096 + wid * 512);                                   \
  } while (0)
#define STAGE_B(b, h, tt)                                                                    \
  do {                                                                                       \
    GLDS(gB + (size_t)((h) * 128) * K + (size_t)(tt) * 64,                                   \
         lds + 32768 + ((b) * 2 + (h)) * 8192 + wid * 512);                                  \
    GLDS(gB + (size_t)((h) * 128 + 64) * K + (size_t)(tt) * 64,                              \
         lds + 32768 + ((b) * 2 + (h)) * 8192 + 4096 + wid * 512);                           \
  } while (0)

  // ds_read address pieces. A local row = mh*64 + mq*16 + (lane&15) within half wm.
  // B local row = (wn&1)*64 + nh*32 + nq*16 + (lane&15) within half wn>>1.
  // swizzled chunk = (kk*4 + (lane>>4)) ^ (lane&7)   [row&7 == lane&7, 0-conflict proven]
  const int l15 = lane & 15;
  const int sw0 = (((lane >> 4)) ^ (lane & 7)) << 3;        // kk=0
  const int sw1 = ((4 + (lane >> 4)) ^ (lane & 7)) << 3;    // kk=1
  const int abase = wm * 8192;              // + dbuf*16384? no: slot = (b*2+wm)*8192
  const int bbase = 32768 + ((wn >> 1)) * 8192;
  const int brow0 = ((wn & 1) * 64 + l15) * 64;             // + nh*2048 + nq*1024

  f32x4 acc[8][4] = {};
  bf16x8 Af[8], Bf[4];

  // prologue: all 4 halves of tile 0 -> buf 0
  STAGE_A(0, 0, 0); STAGE_A(0, 1, 0); STAGE_B(0, 0, 0); STAGE_B(0, 1, 0);
  asm volatile("s_waitcnt vmcnt(0)" ::: "memory");
  __builtin_amdgcn_s_barrier();

  for (int t = 0; t < NT; ++t) {
    const int b = t & 1, nb = b ^ 1;
    const bool st = (t + 1 < NT);
    const int aA = (b * 2 + wm) * 8192 + l15 * 64;          // + mh*4096 + mq*1024
    const int aB = bbase + b * 16384 + brow0;               // + nh*2048 + nq*1024

    // ---- P1 (mh=0, nh=0): stage A0',B1'; read Af[8](mh0), Bf[4](nh0); 16 MFMA ----
    if (st) { STAGE_A(nb, 0, t + 1); STAGE_B(nb, 1, t + 1); }
#pragma unroll
    for (int mq = 0; mq < 4; ++mq) {
      Af[mq * 2]     = *(const bf16x8*)&lds[aA + mq * 1024 + sw0];
      Af[mq * 2 + 1] = *(const bf16x8*)&lds[aA + mq * 1024 + sw1];
    }
#pragma unroll
    for (int nq = 0; nq < 2; ++nq) {
      Bf[nq * 2]     = *(const bf16x8*)&lds[aB + nq * 1024 + sw0];
      Bf[nq * 2 + 1] = *(const bf16x8*)&lds[aB + nq * 1024 + sw1];
    }
    PHASE_FENCE_PRE();
    __builtin_amdgcn_s_barrier();
    PHASE_FENCE_POST();
    __builtin_amdgcn_s_setprio(1);
#pragma unroll
    for (int mq = 0; mq < 4; ++mq)
#pragma unroll
      for (int nq = 0; nq < 2; ++nq)
#pragma unroll
        for (int kk = 0; kk < 2; ++kk)
          acc[mq][nq] = __builtin_amdgcn_mfma_f32_16x16x32_bf16(
              Af[mq * 2 + kk], Bf[nq * 2 + kk], acc[mq][nq], 0, 0, 0);
    __builtin_amdgcn_s_setprio(0);
    __builtin_amdgcn_s_barrier();

    // ---- P2 (mh=1, nh=0): stage B0'; read Af[8](mh1); reuse Bf; 16 MFMA ----
    if (st) STAGE_B(nb, 0, t + 1);
#pragma unroll
    for (int mq = 0; mq < 4; ++mq) {
      Af[mq * 2]     = *(const bf16x8*)&lds[aA + 4096 + mq * 1024 + sw0];
      Af[mq * 2 + 1] = *(const bf16x8*)&lds[aA + 4096 + mq * 1024 + sw1];
    }
    PHASE_FENCE_PRE();
    __builtin_amdgcn_s_barrier();
    PHASE_FENCE_POST();
    __builtin_amdgcn_s_setprio(1);
#pragma unroll
    for (int mq = 0; mq < 4; ++mq)
#pragma unroll
      for (int nq = 0; nq < 2; ++nq)
#pragma unroll
        for (int kk = 0; kk < 2; ++kk)
          acc[4 + mq][nq] = __builtin_amdgcn_mfma_f32_16x16x32_bf16(
              Af[mq * 2 + kk], Bf[nq * 2 + kk], acc[4 + mq][nq], 0, 0, 0);
    __builtin_amdgcn_s_setprio(0);
    __builtin_amdgcn_s_barrier();

    // ---- P3 (mh=1, nh=1): stage A1'; read Bf[4](nh1); reuse Af; 16 MFMA ----
    if (st) STAGE_A(nb, 1, t + 1);
#pragma unroll
    for (int nq = 0; nq < 2; ++nq) {
      Bf[nq * 2]     = *(const bf16x8*)&lds[aB + 2048 + nq * 1024 + sw0];
      Bf[nq * 2 + 1] = *(const bf16x8*)&lds[aB + 2048 + nq * 1024 + sw1];
    }
    PHASE_FENCE_PRE();
    __builtin_amdgcn_s_barrier();
    PHASE_FENCE_POST();
    __builtin_amdgcn_s_setprio(1);
#pragma unroll
    for (int mq = 0; mq < 4; ++mq)
#pragma unroll
      for (int nq = 0; nq < 2; ++nq)
#pragma unroll
        for (int kk = 0; kk < 2; ++kk)
          acc[4 + mq][2 + nq] = __builtin_amdgcn_mfma_f32_16x16x32_bf16(
              Af[mq * 2 + kk], Bf[nq * 2 + kk], acc[4 + mq][2 + nq], 0, 0, 0);
    __builtin_amdgcn_s_setprio(0);
    __builtin_amdgcn_s_barrier();

    // ---- P4 (mh=0, nh=1): read Af[8](mh0); reuse Bf; 16 MFMA; tile drain ----
#pragma unroll
    for (int mq = 0; mq < 4; ++mq) {
      Af[mq * 2]     = *(const bf16x8*)&lds[aA + mq * 1024 + sw0];
      Af[mq * 2 + 1] = *(const bf16x8*)&lds[aA + mq * 1024 + sw1];
    }
    PHASE_FENCE_PRE();
    __builtin_amdgcn_s_barrier();
    PHASE_FENCE_POST();
    __builtin_amdgcn_s_setprio(1);
#pragma unroll
    for (int mq = 0; mq < 4; ++mq)
#pragma unroll
      for (int nq = 0; nq < 2; ++nq)
#pragma unroll
        for (int kk = 0; kk < 2; ++kk)
          acc[mq][2 + nq] = __builtin_amdgcn_mfma_f32_16x16x32_bf16(
              Af[mq * 2 + kk], Bf[nq * 2 + kk], acc[mq][2 + nq], 0, 0, 0);
    __builtin_amdgcn_s_setprio(0);
    if (st) asm volatile("s_waitcnt vmcnt(0)" ::: "memory");
    __builtin_amdgcn_s_barrier();
  }

  // ---------------- featmap epilogue: one head per wave ----------------
  const int head = bx * 4 + wn;     // 0..95, uniform per wave
  const int type = head >> 5;       // 0 Q, 1 K, 2 V
  const int h = head & 31;
  const float* bias = (type == 0) ? bq : (type == 1) ? bk : bv;
  unsigned short* dst = (type == 0) ? oQ : (type == 1) ? oK : oV;
  float bv4[4];
#pragma unroll
  for (int n = 0; n < 4; ++n) bv4[n] = bias[h * 64 + n * 16 + l15];
#pragma unroll
  for (int m = 0; m < 8; ++m) {
#pragma unroll
    for (int r = 0; r < 4; ++r) {
      const int row = by * 256 + wm * 128 + m * 16 + ((lane >> 4) << 2) + r;
      const int bb = row >> 11, s = row & 2047;
      float e[4];
      float loc = 0.f;
#pragma unroll
      for (int n = 0; n < 4; ++n) {
        float v = acc[m][n][r] + bv4[n];
        if (type == 0) v *= 0.125f;
        if (type < 2) v = (v > 0.f) ? (v + 1.f) : __expf(v);
        e[n] = v; loc += v;
      }
      if (type < 2) {
#pragma unroll
        for (int off = 1; off < 16; off <<= 1) loc += __shfl_xor(loc, off, 64);
        const float inv = 1.f / (loc + 1e-4f);
#pragma unroll
        for (int n = 0; n < 4; ++n) e[n] *= inv;
      }
      const size_t base = ((size_t)((bb << 5) + h) * 2048 + s) * 64;
#pragma unroll
      for (int n = 0; n < 4; ++n) dst[base + n * 16 + l15] = f2bf(e[n]);
    }
  }
#undef STAGE_A
#undef STAGE_B
}

// ---------------- wo GEMM: BM=128 BN=256 BK=64, 3-buf, grid 256 (proven) ----------------
__global__ __launch_bounds__(512, 2) void gemm128_wo(
    const unsigned short* __restrict__ A, const unsigned short* __restrict__ Bw,
    const float* __restrict__ b0, float* __restrict__ C) {
  constexpr int K = 2048, NT = 32;
  __shared__ unsigned short lds[73728];
  const int tid = threadIdx.x, lane = tid & 63, wid = tid >> 6;
  const int wm = wid >> 2, wn = wid & 3;

  const int g0 = blockIdx.x;
  const int wg = (g0 & 7) * 32 + (g0 >> 3);
  const int l = wg % 32;
  const int chunk = wg / 32;
  const int bx2 = (chunk % 4) * 2 + l / 16;
  const int by2 = (chunk / 4) * 16 + l % 16;

  const int rloc = wid * 8 + (lane >> 3);
  const size_t gcoff = (size_t)(((lane & 7) ^ (lane >> 3)) << 3);
  const unsigned short* gA[2];
  const unsigned short* gB[4];
#pragma unroll
  for (int c = 0; c < 2; ++c) gA[c] = A + (size_t)(by2 * 128 + c * 64 + rloc) * K + gcoff;
#pragma unroll
  for (int c = 0; c < 4; ++c) gB[c] = Bw + (size_t)(bx2 * 256 + c * 64 + rloc) * K + gcoff;

  int aoff[4][2], boff[4][2];
#pragma unroll
  for (int m = 0; m < 4; ++m)
#pragma unroll
    for (int kk = 0; kk < 2; ++kk) {
      aoff[m][kk] = (wm * 64 + m * 16 + (lane & 15)) * 64 +
                    ((((kk << 2) + (lane >> 4)) ^ (lane & 7)) << 3);
      boff[m][kk] = (wn * 64 + m * 16 + (lane & 15)) * 64 +
                    ((((kk << 2) + (lane >> 4)) ^ (lane & 7)) << 3);
    }

  f32x4 acc[4][4] = {};

#define AB(b) ((b) * 8192)
#define BB(b) (24576 + (b) * 16384)
#define STAGE_A(c, b) GLDS(gA[c], lds + AB(b) + (c) * 4096 + wid * 512)
#define STAGE_B(c, b) GLDS(gB[c], lds + BB(b) + (c) * 4096 + wid * 512)

  STAGE_A(0, 0); STAGE_A(1, 0); STAGE_B(0, 0); STAGE_B(1, 0); STAGE_B(2, 0); STAGE_B(3, 0);
#pragma unroll
  for (int c = 0; c < 2; ++c) gA[c] += 64;
#pragma unroll
  for (int c = 0; c < 4; ++c) gB[c] += 64;
  STAGE_A(0, 1); STAGE_A(1, 1); STAGE_B(0, 1); STAGE_B(1, 1); STAGE_B(2, 1); STAGE_B(3, 1);
#pragma unroll
  for (int c = 0; c < 2; ++c) gA[c] += 64;
#pragma unroll
  for (int c = 0; c < 4; ++c) gB[c] += 64;
  asm volatile("s_waitcnt vmcnt(6)" ::: "memory");
  __builtin_amdgcn_s_barrier();

  for (int t = 0; t < NT; ++t) {
    const int b = t % 3;
    const int sb = (t + 2) % 3;
    const bool doStage = (t + 2 < NT);

    if (doStage) { STAGE_A(0, sb); STAGE_A(1, sb); STAGE_B(0, sb); STAGE_B(1, sb); }
    bf16x8 af[4], bfr[4];
#pragma unroll
    for (int m = 0; m < 4; ++m) af[m] = *(const bf16x8*)&lds[AB(b) + aoff[m][0]];
#pragma unroll
    for (int n = 0; n < 4; ++n) bfr[n] = *(const bf16x8*)&lds[BB(b) + boff[n][0]];
    PHASE_FENCE_PRE();
    __builtin_amdgcn_s_barrier();
    PHASE_FENCE_POST();
    __builtin_amdgcn_s_setprio(1);
#pragma unroll
    for (int m = 0; m < 4; ++m)
#pragma unroll
      for (int n = 0; n < 4; ++n)
        acc[m][n] = __builtin_amdgcn_mfma_f32_16x16x32_bf16(af[m], bfr[n], acc[m][n], 0, 0, 0);
    __builtin_amdgcn_s_setprio(0);
    __builtin_amdgcn_s_barrier();

    if (doStage) { STAGE_B(2, sb); STAGE_B(3, sb); }
#pragma unroll
    for (int c = 0; c < 2; ++c) gA[c] += 64;
#pragma unroll
    for (int c = 0; c < 4; ++c) gB[c] += 64;
#pragma unroll
    for (int m = 0; m < 4; ++m) af[m] = *(const bf16x8*)&lds[AB(b) + aoff[m][1]];
#pragma unroll
    for (int n = 0; n < 4; ++n) bfr[n] = *(const bf16x8*)&lds[BB(b) + boff[n][1]];
    PHASE_FENCE_PRE();
    __builtin_amdgcn_s_barrier();
    PHASE_FENCE_POST();
    __builtin_amdgcn_s_setprio(1);
#pragma unroll
    for (int m = 0; m < 4; ++m)
#pragma unroll
      for (int n = 0; n < 4; ++n)
        acc[m][n] = __builtin_amdgcn_mfma_f32_16x16x32_bf16(af[m], bfr[n], acc[m][n], 0, 0, 0);
    __builtin_amdgcn_s_setprio(0);
    if (t < NT - 1) {
      if (doStage) asm volatile("s_waitcnt vmcnt(6)" ::: "memory");
      else         asm volatile("s_waitcnt vmcnt(0)" ::: "memory");
    }
    __builtin_amdgcn_s_barrier();
  }

#pragma unroll
  for (int n = 0; n < 4; ++n) {
    const int col = bx2 * 256 + wn * 64 + n * 16 + (lane & 15);
    const float bv_ = b0[col];
#pragma unroll
    for (int m = 0; m < 4; ++m) {
      const int row0 = by2 * 128 + wm * 64 + m * 16 + ((lane >> 4) << 2);
#pragma unroll
      for (int r = 0; r < 4; ++r)
        C[(size_t)(row0 + r) * 2048 + col] = acc[m][n][r] + bv_;
    }
  }
#undef AB
#undef BB
#undef STAGE_A
#undef STAGE_B
}

// ---------------- pass1: per-chunk stateT[d][e] = sum_t v[t,d]*k[t,e] ----------------
__global__ __launch_bounds__(256) void chunk_state(
    const unsigned short* __restrict__ Kn, const unsigned short* __restrict__ Vn,
    unsigned short* __restrict__ stT) {
  __shared__ unsigned short Kt[64 * 72];
  __shared__ unsigned short Vt[64 * 72];
  const int c = blockIdx.x, bh = blockIdx.y;
  const int tid = threadIdx.x, lane = tid & 63, wid = tid >> 6;
  const size_t base = (size_t)bh * 2048 * 64 + (size_t)c * 64 * 64;
#pragma unroll
  for (int i = 0; i < 16; ++i) {
    const int ii = i * 256 + tid;
    const int t = ii >> 6, d = ii & 63;
    Kt[d * 72 + t] = Kn[base + ii];
    Vt[d * 72 + t] = Vn[base + ii];
  }
  __syncthreads();
  f32x4 acc[4] = {};
#pragma unroll
  for (int ks = 0; ks < 2; ++ks) {
    const int ko = ks * 32 + (lane >> 4) * 8;
    bf16x8 a = *(const bf16x8*)&Vt[(wid * 16 + (lane & 15)) * 72 + ko];
#pragma unroll
    for (int ej = 0; ej < 4; ++ej) {
      bf16x8 bb = *(const bf16x8*)&Kt[(ej * 16 + (lane & 15)) * 72 + ko];
      acc[ej] = __builtin_amdgcn_mfma_f32_16x16x32_bf16(a, bb, acc[ej], 0, 0, 0);
    }
  }
  const size_t obase = ((size_t)bh * 32 + c) * 4096;
#pragma unroll
  for (int ej = 0; ej < 4; ++ej) {
    const int e = ej * 16 + (lane & 15);
    const int d0 = wid * 16 + ((lane >> 4) << 2);
#pragma unroll
    for (int r = 0; r < 4; ++r)
      stT[obase + (size_t)(d0 + r) * 64 + e] = f2bf(acc[ej][r]);
  }
}

// ---------------- pass2: exclusive prefix over chunks ----------------
__global__ __launch_bounds__(256) void prefix_state(
    const unsigned short* __restrict__ stT, unsigned short* __restrict__ cumT) {
  const int g = blockIdx.x * 256 + threadIdx.x;
  const int bh = g >> 12, e = g & 4095;
  float run = 0.f;
  for (int c = 0; c < 32; ++c) {
    const size_t idx = (((size_t)bh * 32 + c) << 12) + e;
    const float v = bf2f(stT[idx]);
    cumT[idx] = f2bf(run);
    run += v;
  }
}

// ---------------- pass3: out = (tril(Q K^T) V + Q stateT) * 0.125 ----------------
__global__ __launch_bounds__(256) void attn_intra(
    const unsigned short* __restrict__ Qn, const unsigned short* __restrict__ Kn,
    const unsigned short* __restrict__ Vn, const unsigned short* __restrict__ cumT,
    unsigned short* __restrict__ aout) {
  __shared__ unsigned short Qs[64 * 72];
  __shared__ unsigned short Ks[64 * 72];
  __shared__ unsigned short Vt[64 * 72];
  __shared__ unsigned short St[64 * 72];
  __shared__ unsigned short Ps[64 * 72];
  const int c = blockIdx.x, bh = blockIdx.y;
  const int tid = threadIdx.x, lane = tid & 63, wid = tid >> 6;
  const size_t base = (size_t)bh * 2048 * 64 + (size_t)c * 64 * 64;
  const size_t sbase = ((size_t)bh * 32 + c) * 4096;
#pragma unroll
  for (int i = 0; i < 16; ++i) {
    const int ii = i * 256 + tid;
    const int t = ii >> 6, d = ii & 63;
    Qs[t * 72 + d] = Qn[base + ii];
    Ks[t * 72 + d] = Kn[base + ii];
    Vt[d * 72 + t] = Vn[base + ii];
    St[t * 72 + d] = cumT[sbase + ii];
  }
  __syncthreads();
  f32x4 sacc[4] = {};
#pragma unroll
  for (int ks = 0; ks < 2; ++ks) {
    const int ko = ks * 32 + (lane >> 4) * 8;
    bf16x8 a = *(const bf16x8*)&Qs[(wid * 16 + (lane & 15)) * 72 + ko];
#pragma unroll
    for (int tj = 0; tj < 4; ++tj) {
      bf16x8 bb = *(const bf16x8*)&Ks[(tj * 16 + (lane & 15)) * 72 + ko];
      sacc[tj] = __builtin_amdgcn_mfma_f32_16x16x32_bf16(a, bb, sacc[tj], 0, 0, 0);
    }
  }
#pragma unroll
  for (int tj = 0; tj < 4; ++tj) {
    const int t = tj * 16 + (lane & 15);
    const int s0 = wid * 16 + ((lane >> 4) << 2);
#pragma unroll
    for (int r = 0; r < 4; ++r) {
      const float v = (t <= s0 + r) ? sacc[tj][r] : 0.f;
      Ps[(s0 + r) * 72 + t] = f2bf(v);
    }
  }
  __syncthreads();
  f32x4 oacc[4] = {};
#pragma unroll
  for (int ks = 0; ks < 2; ++ks) {
    const int ko = ks * 32 + (lane >> 4) * 8;
    bf16x8 a = *(const bf16x8*)&Ps[(wid * 16 + (lane & 15)) * 72 + ko];
    bf16x8 a2 = *(const bf16x8*)&Qs[(wid * 16 + (lane & 15)) * 72 + ko];
#pragma unroll
    for (int dj = 0; dj < 4; ++dj) {
      bf16x8 bv_ = *(const bf16x8*)&Vt[(dj * 16 + (lane & 15)) * 72 + ko];
      oacc[dj] = __builtin_amdgcn_mfma_f32_16x16x32_bf16(a, bv_, oacc[dj], 0, 0, 0);
      bf16x8 bs_ = *(const bf16x8*)&St[(dj * 16 + (lane & 15)) * 72 + ko];
      oacc[dj] = __builtin_amdgcn_mfma_f32_16x16x32_bf16(a2, bs_, oacc[dj], 0, 0, 0);
    }
  }
  const int b = bh >> 5, h = bh & 31;
#pragma unroll
  for (int dj = 0; dj < 4; ++dj) {
    const int d = dj * 16 + (lane & 15);
    const int s0 = wid * 16 + ((lane >> 4) << 2);
#pragma unroll
    for (int r = 0; r < 4; ++r) {
      const size_t row = (size_t)(b * 2048 + c * 64 + s0 + r);
      aout[row * 2048 + h * 64 + d] = f2bf(0.125f * oacc[dj][r]);
    }
  }
}

extern "C" void kernel_launch(void* const* d_in, const int* in_sizes, int n_in,
                              void* d_out, int out_size, void* d_ws, size_t ws_size,
                              hipStream_t stream) {
  const float* hs = (const float*)d_in[0];
  const float* wq = (const float*)d_in[2];
  const float* bq = (const float*)d_in[3];
  const float* wk = (const float*)d_in[4];
  const float* bk = (const float*)d_in[5];
  const float* wv = (const float*)d_in[6];
  const float* bv = (const float*)d_in[7];
  const float* wo = (const float*)d_in[8];
  const float* bo = (const float*)d_in[9];
  float* out = (float*)d_out;
  char* ws = (char*)d_ws;

  unsigned short* hs_bf   = (unsigned short*)(ws);               // 16 MiB
  unsigned short* wall_bf = (unsigned short*)(ws + 16777216);    // 32 MiB [wq|wk|wv|wo]
  unsigned short* Qn      = (unsigned short*)(ws + 50331648);
  unsigned short* Kn      = (unsigned short*)(ws + 67108864);
  unsigned short* Vn      = (unsigned short*)(ws + 83886080);
  unsigned short* stT     = (unsigned short*)(ws + 100663296);
  unsigned short* cumT    = (unsigned short*)(ws + 117440512);
  unsigned short* aout    = (unsigned short*)(ws + 134217728);

  cvt_f32_bf16<<<8192, 256, 0, stream>>>(hs, hs_bf, 2097152);
  cvt_w4<<<dim3(4096, 4), 256, 0, stream>>>(wq, wk, wv, wo, wall_bf);

  // fused QKV projection + feature map (m201-style 256x256 8-phase, grid 384)
  gemm256_qkv<<<384, 512, 0, stream>>>(hs_bf, wall_bf, bq, bk, bv, Qn, Kn, Vn);

  chunk_state<<<dim3(32, 64), 256, 0, stream>>>(Kn, Vn, stT);
  prefix_state<<<1024, 256, 0, stream>>>(stT, cumT);
  attn_intra<<<dim3(32, 64), 256, 0, stream>>>(Qn, Kn, Vn, cumT, aout);

  gemm128_wo<<<256, 512, 0, stream>>>(aout, wall_bf + 12582912, bo, out);
}

// Round 9
// 197.988 us; speedup vs baseline: 1.2007x; 1.2007x over previous
//
#include <hip/hip_runtime.h>

typedef __bf16 bf16x8 __attribute__((ext_vector_type(8)));
typedef float f32x4 __attribute__((ext_vector_type(4)));

#define GLDS(g, l) __builtin_amdgcn_global_load_lds(                              \
    (const __attribute__((address_space(1))) void*)(g),                            \
    (__attribute__((address_space(3))) void*)(l), 16, 0, 0)

__device__ __forceinline__ unsigned short f2bf(float f) {
  unsigned int u = __builtin_bit_cast(unsigned int, f);
  u = (u + 0x7fffu + ((u >> 16) & 1u)) >> 16;
  return (unsigned short)u;
}
__device__ __forceinline__ float bf2f(unsigned short h) {
  unsigned int u = ((unsigned int)h) << 16;
  return __builtin_bit_cast(float, u);
}

// ---------------- merged convert: hs (2M float4) + 4 weights (1M float4 each) ----------------
__global__ __launch_bounds__(256) void cvt_all(
    const float* __restrict__ hs, const float* __restrict__ w0,
    const float* __restrict__ w1, const float* __restrict__ w2,
    const float* __restrict__ w3, unsigned short* __restrict__ hs_bf,
    unsigned short* __restrict__ wall_bf) {
  const int i = blockIdx.x * 256 + threadIdx.x;   // 0..6291455
  const float* src;
  unsigned short* dst;
  int off;
  if (i < 2097152) { src = hs; dst = hs_bf; off = i; }
  else {
    const int j = i - 2097152;
    const int y = j >> 20;                        // 0..3
    src = (y == 0) ? w0 : (y == 1) ? w1 : (y == 2) ? w2 : w3;
    dst = wall_bf + (size_t)y * 4194304;
    off = j & 1048575;
  }
  float4 v = ((const float4*)src)[off];
  ushort4 o;
  o.x = f2bf(v.x); o.y = f2bf(v.y); o.z = f2bf(v.z); o.w = f2bf(v.w);
  ((ushort4*)dst)[off] = o;
}

// ============ QKV GEMM (R4 config, best measured): BM=256 BN=384 BK=64, grid 256 exact ============
// 8 waves as 4M x 2N: wave tile 64 x 192 = 3 whole heads. acc[4][12].
// LDS: A 2x32KB + B 2x48KB = 160KB exact. Stages issued ph0-2, vmcnt(0) at tile end.
__global__ __launch_bounds__(512, 2) void gemm384_qkv(
    const unsigned short* __restrict__ A, const unsigned short* __restrict__ Bw,
    const float* __restrict__ bq, const float* __restrict__ bk, const float* __restrict__ bv,
    unsigned short* __restrict__ oQ, unsigned short* __restrict__ oK,
    unsigned short* __restrict__ oV) {
  constexpr int K = 2048, NT = 32;
  __shared__ unsigned short lds[81920];   // A: 2 x 16384 us @0, B: 2 x 24576 us @32768
  const int tid = threadIdx.x, lane = tid & 63, wid = tid >> 6;
  const int wm = wid >> 1, wn = wid & 1;

  // XCD bijective swizzle; 8 chunks of 4x8 tiles
  const int g0 = blockIdx.x;
  const int wg = (g0 & 7) * 32 + (g0 >> 3);
  const int chunk = wg >> 5, l = wg & 31;
  const int bx = (chunk & 3) * 4 + (l >> 3);   // 0..15 N-tiles (384 wide)
  const int by = (chunk >> 2) * 8 + (l & 7);   // 0..15 M-tiles (256 tall)

  const int rloc = tid >> 3;                              // 0..63 row within 64-row call
  const size_t gcoff = (size_t)(((lane & 7) ^ (lane >> 3)) << 3);
  const unsigned short* gA = A  + (size_t)(by * 256 + rloc) * K + gcoff;
  const unsigned short* gB = Bw + (size_t)(bx * 384 + rloc) * K + gcoff;

#define ABu(b) ((b) * 16384)
#define BBu(b) (32768 + (b) * 24576)
#define STAGE_A(c, b) GLDS(gA + (size_t)(c) * 64 * K, lds + ABu(b) + (c) * 4096 + wid * 512)
#define STAGE_B(c, b) GLDS(gB + (size_t)(c) * 64 * K, lds + BBu(b) + (c) * 4096 + wid * 512)

  // ds_read pieces (swizzled chunk = q ^ (row&7); 0-conflict measured)
  const int arow = (wm * 64 + (lane & 15)) * 64;    // + m*1024
  const int brow = (wn * 192 + (lane & 15)) * 64;   // + n*1024
  const int sw0 = (((lane >> 4)) ^ (lane & 7)) << 3;
  const int sw1 = ((4 + (lane >> 4)) ^ (lane & 7)) << 3;

  f32x4 acc[4][12] = {};

  // prologue: tile 0 -> buf 0
  STAGE_A(0, 0); STAGE_A(1, 0); STAGE_A(2, 0); STAGE_A(3, 0);
  STAGE_B(0, 0); STAGE_B(1, 0); STAGE_B(2, 0); STAGE_B(3, 0); STAGE_B(4, 0); STAGE_B(5, 0);
  gA += 64; gB += 64;
  asm volatile("s_waitcnt vmcnt(0)" ::: "memory");
  __builtin_amdgcn_s_barrier();

  for (int t = 0; t < NT; ++t) {
    const int Ab = ABu(t & 1) + arow;
    const int Bb = BBu(t & 1) + brow;
    const int sb = (t + 1) & 1;
    const bool st = (t + 1 < NT);
    bf16x8 Af[4], Bf[6];

    // ---- phase 0: kk0, n0-5 ----
    if (st) { STAGE_B(0, sb); STAGE_B(1, sb); STAGE_B(2, sb); }
#pragma unroll
    for (int m = 0; m < 4; ++m) Af[m] = *(const bf16x8*)&lds[Ab + m * 1024 + sw0];
#pragma unroll
    for (int n = 0; n < 6; ++n) Bf[n] = *(const bf16x8*)&lds[Bb + n * 1024 + sw0];
    __builtin_amdgcn_s_barrier();
    __builtin_amdgcn_s_setprio(1);
#pragma unroll
    for (int m = 0; m < 4; ++m)
#pragma unroll
      for (int n = 0; n < 6; ++n)
        acc[m][n] = __builtin_amdgcn_mfma_f32_16x16x32_bf16(Af[m], Bf[n], acc[m][n], 0, 0, 0);
    __builtin_amdgcn_s_setprio(0);
    __builtin_amdgcn_s_barrier();

    // ---- phase 1: kk0, n6-11 ----
    if (st) { STAGE_B(3, sb); STAGE_B(4, sb); STAGE_B(5, sb); }
#pragma unroll
    for (int n = 0; n < 6; ++n) Bf[n] = *(const bf16x8*)&lds[Bb + (n + 6) * 1024 + sw0];
    __builtin_amdgcn_s_barrier();
    __builtin_amdgcn_s_setprio(1);
#pragma unroll
    for (int m = 0; m < 4; ++m)
#pragma unroll
      for (int n = 0; n < 6; ++n)
        acc[m][n + 6] = __builtin_amdgcn_mfma_f32_16x16x32_bf16(Af[m], Bf[n], acc[m][n + 6], 0, 0, 0);
    __builtin_amdgcn_s_setprio(0);
    __builtin_amdgcn_s_barrier();

    // ---- phase 2: kk1, n0-5 ----
    if (st) { STAGE_A(0, sb); STAGE_A(1, sb); STAGE_A(2, sb); STAGE_A(3, sb); }
#pragma unroll
    for (int m = 0; m < 4; ++m) Af[m] = *(const bf16x8*)&lds[Ab + m * 1024 + sw1];
#pragma unroll
    for (int n = 0; n < 6; ++n) Bf[n] = *(const bf16x8*)&lds[Bb + n * 1024 + sw1];
    __builtin_amdgcn_s_barrier();
    __builtin_amdgcn_s_setprio(1);
#pragma unroll
    for (int m = 0; m < 4; ++m)
#pragma unroll
      for (int n = 0; n < 6; ++n)
        acc[m][n] = __builtin_amdgcn_mfma_f32_16x16x32_bf16(Af[m], Bf[n], acc[m][n], 0, 0, 0);
    __builtin_amdgcn_s_setprio(0);
    __builtin_amdgcn_s_barrier();

    // ---- phase 3: kk1, n6-11 ----
#pragma unroll
    for (int n = 0; n < 6; ++n) Bf[n] = *(const bf16x8*)&lds[Bb + (n + 6) * 1024 + sw1];
    __builtin_amdgcn_s_barrier();
    __builtin_amdgcn_s_setprio(1);
#pragma unroll
    for (int m = 0; m < 4; ++m)
#pragma unroll
      for (int n = 0; n < 6; ++n)
        acc[m][n + 6] = __builtin_amdgcn_mfma_f32_16x16x32_bf16(Af[m], Bf[n], acc[m][n + 6], 0, 0, 0);
    __builtin_amdgcn_s_setprio(0);
    if (st) {
      gA += 64; gB += 64;
      asm volatile("s_waitcnt vmcnt(0)" ::: "memory");
    }
    __builtin_amdgcn_s_barrier();
  }

  // ---------------- featmap epilogue: 3 whole heads per wave ----------------
  const int head0 = bx * 6 + wn * 3;
#pragma unroll
  for (int g = 0; g < 3; ++g) {
    const int head = head0 + g;       // uniform per wave
    const int type = head >> 5;       // 0 Q, 1 K, 2 V
    const int h = head & 31;
    const float* bias = (type == 0) ? bq : (type == 1) ? bk : bv;
    unsigned short* dst = (type == 0) ? oQ : (type == 1) ? oK : oV;
    float bv4[4];
#pragma unroll
    for (int j = 0; j < 4; ++j) bv4[j] = bias[h * 64 + j * 16 + (lane & 15)];
#pragma unroll
    for (int m = 0; m < 4; ++m) {
#pragma unroll
      for (int r = 0; r < 4; ++r) {
        const int row = by * 256 + wm * 64 + m * 16 + ((lane >> 4) << 2) + r;
        const int bb = row >> 11, s = row & 2047;
        float e[4];
        float loc = 0.f;
#pragma unroll
        for (int j = 0; j < 4; ++j) {
          float v = acc[m][g * 4 + j][r] + bv4[j];
          if (type == 0) v *= 0.125f;
          if (type < 2) v = (v > 0.f) ? (v + 1.f) : __expf(v);
          e[j] = v; loc += v;
        }
        if (type < 2) {
#pragma unroll
          for (int off = 1; off < 16; off <<= 1) loc += __shfl_xor(loc, off, 64);
          const float inv = 1.f / (loc + 1e-4f);
#pragma unroll
          for (int j = 0; j < 4; ++j) e[j] *= inv;
        }
        const size_t base = ((size_t)((bb << 5) + h) * 2048 + s) * 64;
#pragma unroll
        for (int j = 0; j < 4; ++j) dst[base + j * 16 + (lane & 15)] = f2bf(e[j]);
      }
    }
  }
#undef ABu
#undef BBu
#undef STAGE_A
#undef STAGE_B
}

// ---------------- wo GEMM (proven): BM=128 BN=256 BK=64, 3-buf, grid 256 ----------------
__global__ __launch_bounds__(512, 2) void gemm128_wo(
    const unsigned short* __restrict__ A, const unsigned short* __restrict__ Bw,
    const float* __restrict__ b0, float* __restrict__ C) {
  constexpr int K = 2048, NT = 32;
  __shared__ unsigned short lds[73728];
  const int tid = threadIdx.x, lane = tid & 63, wid = tid >> 6;
  const int wm = wid >> 2, wn = wid & 3;

  const int g0 = blockIdx.x;
  const int wg = (g0 & 7) * 32 + (g0 >> 3);
  const int l = wg % 32;
  const int chunk = wg / 32;
  const int bx2 = (chunk % 4) * 2 + l / 16;
  const int by2 = (chunk / 4) * 16 + l % 16;

  const int rloc = wid * 8 + (lane >> 3);
  const size_t gcoff = (size_t)(((lane & 7) ^ (lane >> 3)) << 3);
  const unsigned short* gA[2];
  const unsigned short* gB[4];
#pragma unroll
  for (int c = 0; c < 2; ++c) gA[c] = A + (size_t)(by2 * 128 + c * 64 + rloc) * K + gcoff;
#pragma unroll
  for (int c = 0; c < 4; ++c) gB[c] = Bw + (size_t)(bx2 * 256 + c * 64 + rloc) * K + gcoff;

  int aoff[4][2], boff[4][2];
#pragma unroll
  for (int m = 0; m < 4; ++m)
#pragma unroll
    for (int kk = 0; kk < 2; ++kk) {
      aoff[m][kk] = (wm * 64 + m * 16 + (lane & 15)) * 64 +
                    ((((kk << 2) + (lane >> 4)) ^ (lane & 7)) << 3);
      boff[m][kk] = (wn * 64 + m * 16 + (lane & 15)) * 64 +
                    ((((kk << 2) + (lane >> 4)) ^ (lane & 7)) << 3);
    }

  f32x4 acc[4][4] = {};

#define AB(b) ((b) * 8192)
#define BB(b) (24576 + (b) * 16384)
#define STAGE_A(c, b) GLDS(gA[c], lds + AB(b) + (c) * 4096 + wid * 512)
#define STAGE_B(c, b) GLDS(gB[c], lds + BB(b) + (c) * 4096 + wid * 512)

  STAGE_A(0, 0); STAGE_A(1, 0); STAGE_B(0, 0); STAGE_B(1, 0); STAGE_B(2, 0); STAGE_B(3, 0);
#pragma unroll
  for (int c = 0; c < 2; ++c) gA[c] += 64;
#pragma unroll
  for (int c = 0; c < 4; ++c) gB[c] += 64;
  STAGE_A(0, 1); STAGE_A(1, 1); STAGE_B(0, 1); STAGE_B(1, 1); STAGE_B(2, 1); STAGE_B(3, 1);
#pragma unroll
  for (int c = 0; c < 2; ++c) gA[c] += 64;
#pragma unroll
  for (int c = 0; c < 4; ++c) gB[c] += 64;
  asm volatile("s_waitcnt vmcnt(6)" ::: "memory");
  __builtin_amdgcn_s_barrier();

  for (int t = 0; t < NT; ++t) {
    const int b = t % 3;
    const int sb = (t + 2) % 3;
    const bool doStage = (t + 2 < NT);

    if (doStage) { STAGE_A(0, sb); STAGE_A(1, sb); STAGE_B(0, sb); STAGE_B(1, sb); }
    bf16x8 af[4], bfr[4];
#pragma unroll
    for (int m = 0; m < 4; ++m) af[m] = *(const bf16x8*)&lds[AB(b) + aoff[m][0]];
#pragma unroll
    for (int n = 0; n < 4; ++n) bfr[n] = *(const bf16x8*)&lds[BB(b) + boff[n][0]];
    __builtin_amdgcn_s_barrier();
    __builtin_amdgcn_s_setprio(1);
#pragma unroll
    for (int m = 0; m < 4; ++m)
#pragma unroll
      for (int n = 0; n < 4; ++n)
        acc[m][n] = __builtin_amdgcn_mfma_f32_16x16x32_bf16(af[m], bfr[n], acc[m][n], 0, 0, 0);
    __builtin_amdgcn_s_setprio(0);
    __builtin_amdgcn_s_barrier();

    if (doStage) { STAGE_B(2, sb); STAGE_B(3, sb); }
#pragma unroll
    for (int c = 0; c < 2; ++c) gA[c] += 64;
#pragma unroll
    for (int c = 0; c < 4; ++c) gB[c] += 64;
#pragma unroll
    for (int m = 0; m < 4; ++m) af[m] = *(const bf16x8*)&lds[AB(b) + aoff[m][1]];
#pragma unroll
    for (int n = 0; n < 4; ++n) bfr[n] = *(const bf16x8*)&lds[BB(b) + boff[n][1]];
    __builtin_amdgcn_s_barrier();
    __builtin_amdgcn_s_setprio(1);
#pragma unroll
    for (int m = 0; m < 4; ++m)
#pragma unroll
      for (int n = 0; n < 4; ++n)
        acc[m][n] = __builtin_amdgcn_mfma_f32_16x16x32_bf16(af[m], bfr[n], acc[m][n], 0, 0, 0);
    __builtin_amdgcn_s_setprio(0);
    if (t < NT - 1) {
      if (doStage) asm volatile("s_waitcnt vmcnt(6)" ::: "memory");
      else         asm volatile("s_waitcnt vmcnt(0)" ::: "memory");
    }
    __builtin_amdgcn_s_barrier();
  }

#pragma unroll
  for (int n = 0; n < 4; ++n) {
    const int col = bx2 * 256 + wn * 64 + n * 16 + (lane & 15);
    const float bv_ = b0[col];
#pragma unroll
    for (int m = 0; m < 4; ++m) {
      const int row0 = by2 * 128 + wm * 64 + m * 16 + ((lane >> 4) << 2);
#pragma unroll
      for (int r = 0; r < 4; ++r)
        C[(size_t)(row0 + r) * 2048 + col] = acc[m][n][r] + bv_;
    }
  }
#undef AB
#undef BB
#undef STAGE_A
#undef STAGE_B
}

// ---------------- pass1: per-chunk stateT[d][e] = sum_t v[t,d]*k[t,e] ----------------
__global__ __launch_bounds__(256) void chunk_state(
    const unsigned short* __restrict__ Kn, const unsigned short* __restrict__ Vn,
    unsigned short* __restrict__ stT) {
  __shared__ unsigned short Kt[64 * 72];
  __shared__ unsigned short Vt[64 * 72];
  const int c = blockIdx.x, bh = blockIdx.y;
  const int tid = threadIdx.x, lane = tid & 63, wid = tid >> 6;
  const size_t base = (size_t)bh * 2048 * 64 + (size_t)c * 64 * 64;
#pragma unroll
  for (int i = 0; i < 16; ++i) {
    const int ii = i * 256 + tid;
    const int t = ii >> 6, d = ii & 63;
    Kt[d * 72 + t] = Kn[base + ii];
    Vt[d * 72 + t] = Vn[base + ii];
  }
  __syncthreads();
  f32x4 acc[4] = {};
#pragma unroll
  for (int ks = 0; ks < 2; ++ks) {
    const int ko = ks * 32 + (lane >> 4) * 8;
    bf16x8 a = *(const bf16x8*)&Vt[(wid * 16 + (lane & 15)) * 72 + ko];
#pragma unroll
    for (int ej = 0; ej < 4; ++ej) {
      bf16x8 bb = *(const bf16x8*)&Kt[(ej * 16 + (lane & 15)) * 72 + ko];
      acc[ej] = __builtin_amdgcn_mfma_f32_16x16x32_bf16(a, bb, acc[ej], 0, 0, 0);
    }
  }
  const size_t obase = ((size_t)bh * 32 + c) * 4096;
#pragma unroll
  for (int ej = 0; ej < 4; ++ej) {
    const int e = ej * 16 + (lane & 15);
    const int d0 = wid * 16 + ((lane >> 4) << 2);
#pragma unroll
    for (int r = 0; r < 4; ++r)
      stT[obase + (size_t)(d0 + r) * 64 + e] = f2bf(acc[ej][r]);
  }
}

// ---------------- pass2: exclusive prefix over chunks ----------------
__global__ __launch_bounds__(256) void prefix_state(
    const unsigned short* __restrict__ stT, unsigned short* __restrict__ cumT) {
  const int g = blockIdx.x * 256 + threadIdx.x;
  const int bh = g >> 12, e = g & 4095;
  float run = 0.f;
  for (int c = 0; c < 32; ++c) {
    const size_t idx = (((size_t)bh * 32 + c) << 12) + e;
    const float v = bf2f(stT[idx]);
    cumT[idx] = f2bf(run);
    run += v;
  }
}

// ---------------- pass3: out = (tril(Q K^T) V + Q stateT) * 0.125 ----------------
__global__ __launch_bounds__(256) void attn_intra(
    const unsigned short* __restrict__ Qn, const unsigned short* __restrict__ Kn,
    const unsigned short* __restrict__ Vn, const unsigned short* __restrict__ cumT,
    unsigned short* __restrict__ aout) {
  __shared__ unsigned short Qs[64 * 72];
  __shared__ unsigned short Ks[64 * 72];
  __shared__ unsigned short Vt[64 * 72];
  __shared__ unsigned short St[64 * 72];
  __shared__ unsigned short Ps[64 * 72];
  const int c = blockIdx.x, bh = blockIdx.y;
  const int tid = threadIdx.x, lane = tid & 63, wid = tid >> 6;
  const size_t base = (size_t)bh * 2048 * 64 + (size_t)c * 64 * 64;
  const size_t sbase = ((size_t)bh * 32 + c) * 4096;
#pragma unroll
  for (int i = 0; i < 16; ++i) {
    const int ii = i * 256 + tid;
    const int t = ii >> 6, d = ii & 63;
    Qs[t * 72 + d] = Qn[base + ii];
    Ks[t * 72 + d] = Kn[base + ii];
    Vt[d * 72 + t] = Vn[base + ii];
    St[t * 72 + d] = cumT[sbase + ii];
  }
  __syncthreads();
  f32x4 sacc[4] = {};
#pragma unroll
  for (int ks = 0; ks < 2; ++ks) {
    const int ko = ks * 32 + (lane >> 4) * 8;
    bf16x8 a = *(const bf16x8*)&Qs[(wid * 16 + (lane & 15)) * 72 + ko];
#pragma unroll
    for (int tj = 0; tj < 4; ++tj) {
      bf16x8 bb = *(const bf16x8*)&Ks[(tj * 16 + (lane & 15)) * 72 + ko];
      sacc[tj] = __builtin_amdgcn_mfma_f32_16x16x32_bf16(a, bb, sacc[tj], 0, 0, 0);
    }
  }
#pragma unroll
  for (int tj = 0; tj < 4; ++tj) {
    const int t = tj * 16 + (lane & 15);
    const int s0 = wid * 16 + ((lane >> 4) << 2);
#pragma unroll
    for (int r = 0; r < 4; ++r) {
      const float v = (t <= s0 + r) ? sacc[tj][r] : 0.f;
      Ps[(s0 + r) * 72 + t] = f2bf(v);
    }
  }
  __syncthreads();
  f32x4 oacc[4] = {};
#pragma unroll
  for (int ks = 0; ks < 2; ++ks) {
    const int ko = ks * 32 + (lane >> 4) * 8;
    bf16x8 a = *(const bf16x8*)&Ps[(wid * 16 + (lane & 15)) * 72 + ko];
    bf16x8 a2 = *(const bf16x8*)&Qs[(wid * 16 + (lane & 15)) * 72 + ko];
#pragma unroll
    for (int dj = 0; dj < 4; ++dj) {
      bf16x8 bv_ = *(const bf16x8*)&Vt[(dj * 16 + (lane & 15)) * 72 + ko];
      oacc[dj] = __builtin_amdgcn_mfma_f32_16x16x32_bf16(a, bv_, oacc[dj], 0, 0, 0);
      bf16x8 bs_ = *(const bf16x8*)&St[(dj * 16 + (lane & 15)) * 72 + ko];
      oacc[dj] = __builtin_amdgcn_mfma_f32_16x16x32_bf16(a2, bs_, oacc[dj], 0, 0, 0);
    }
  }
  const int b = bh >> 5, h = bh & 31;
#pragma unroll
  for (int dj = 0; dj < 4; ++dj) {
    const int d = dj * 16 + (lane & 15);
    const int s0 = wid * 16 + ((lane >> 4) << 2);
#pragma unroll
    for (int r = 0; r < 4; ++r) {
      const size_t row = (size_t)(b * 2048 + c * 64 + s0 + r);
      aout[row * 2048 + h * 64 + d] = f2bf(0.125f * oacc[dj][r]);
    }
  }
}

extern "C" void kernel_launch(void* const* d_in, const int* in_sizes, int n_in,
                              void* d_out, int out_size, void* d_ws, size_t ws_size,
                              hipStream_t stream) {
  const float* hs = (const float*)d_in[0];
  const float* wq = (const float*)d_in[2];
  const float* bq = (const float*)d_in[3];
  const float* wk = (const float*)d_in[4];
  const float* bk = (const float*)d_in[5];
  const float* wv = (const float*)d_in[6];
  const float* bv = (const float*)d_in[7];
  const float* wo = (const float*)d_in[8];
  const float* bo = (const float*)d_in[9];
  float* out = (float*)d_out;
  char* ws = (char*)d_ws;

  unsigned short* hs_bf   = (unsigned short*)(ws);               // 16 MiB
  unsigned short* wall_bf = (unsigned short*)(ws + 16777216);    // 32 MiB [wq|wk|wv|wo]
  unsigned short* Qn      = (unsigned short*)(ws + 50331648);
  unsigned short* Kn      = (unsigned short*)(ws + 67108864);
  unsigned short* Vn      = (unsigned short*)(ws + 83886080);
  unsigned short* stT     = (unsigned short*)(ws + 100663296);
  unsigned short* cumT    = (unsigned short*)(ws + 117440512);
  unsigned short* aout    = (unsigned short*)(ws + 134217728);

  // merged convert (hs + all 4 weights) in one dispatch
  cvt_all<<<24576, 256, 0, stream>>>(hs, wq, wk, wv, wo, hs_bf, wall_bf);

  // fused QKV projection + feature map (R4 best-measured config)
  gemm384_qkv<<<256, 512, 0, stream>>>(hs_bf, wall_bf, bq, bk, bv, Qn, Kn, Vn);

  chunk_state<<<dim3(32, 64), 256, 0, stream>>>(Kn, Vn, stT);
  prefix_state<<<1024, 256, 0, stream>>>(stT, cumT);
  attn_intra<<<dim3(32, 64), 256, 0, stream>>>(Qn, Kn, Vn, cumT, aout);

  gemm128_wo<<<256, 512, 0, stream>>>(aout, wall_bf + 12582912, bo, out);
}